// Round 6
// baseline (423.223 us; speedup 1.0000x reference)
//
#include <hip/hip_runtime.h>
#include <hip/hip_bf16.h>

// GCN 2-layer: out = log_softmax(GCN2(relu(GCN1(x))))
// Round 6: software-pipelined GEMMs.
//   gemm1: 2-deep register prefetch of A (fp32->bf16) across unrolled k0 --
//          each wave keeps ~4 global loads in flight behind the MFMAs.
//   gemm2: fully unrolled, all 8 A-loads hoisted ahead of the MFMA chain.
// Sort (block-binned bucket scatter + per-bucket LDS counting sort) and
// quarter-wave aggs unchanged from R5.

#define N_NODES 100000
#define F_IN 256
#define F_MID 128
#define F_OUT 64

#define BSHIFT 8                      // 256 nodes per bucket
#define BNODES 256
#define NBUCKETS ((N_NODES + BNODES - 1) / BNODES)   // 391
#define BCAP 6144                     // mean 4096, sigma ~64 -> +32 sigma
#define EPB 4096                      // edges per scatter block

typedef __attribute__((ext_vector_type(8))) short short8;
typedef __attribute__((ext_vector_type(4))) float f32x4;

__device__ inline ushort bf16_rne(float f) {
    uint u = __float_as_uint(f);
    u += 0x7FFF + ((u >> 16) & 1);
    return (ushort)(u >> 16);
}
__device__ inline float lo16(uint r) { return __uint_as_float(r << 16); }
__device__ inline float hi16(uint r) { return __uint_as_float(r & 0xffff0000u); }
__device__ inline uint pack_bf2(float a, float b) {
    return (uint)bf16_rne(a) | ((uint)bf16_rne(b) << 16);
}

// ---------------- two-level bucket sort ----------------

// S1: block-binned scatter. packed = (dst&255)<<17 | src  (25 bits)
__global__ __launch_bounds__(256)
void bucket_scatter_kernel(const int* __restrict__ src, const int* __restrict__ dst,
                           int* __restrict__ bcur, uint* __restrict__ ebuf, int E) {
    __shared__ int curL[NBUCKETS];
    int t = threadIdx.x;
    int e0 = blockIdx.x * EPB;
    int e1 = e0 + EPB; if (e1 > E) e1 = E;

    for (int i = t; i < NBUCKETS; i += 256) curL[i] = 0;
    __syncthreads();
    for (int i = e0 + t; i < e1; i += 256) atomicAdd(&curL[dst[i] >> BSHIFT], 1);
    __syncthreads();
    for (int i = t; i < NBUCKETS; i += 256) {
        int h = curL[i];
        curL[i] = h ? atomicAdd(&bcur[i], h) : 0;
    }
    __syncthreads();
    for (int i = e0 + t; i < e1; i += 256) {
        int d = dst[i], s = src[i];
        int b = d >> BSHIFT;
        int pos = atomicAdd(&curL[b], 1);
        if (pos < BCAP) ebuf[(size_t)b * BCAP + pos] = ((uint)(d & (BNODES - 1)) << 17) | (uint)s;
    }
}

// S2: per-bucket counting sort; emits ssrc + rs + cnt + dinv.
__global__ __launch_bounds__(256)
void bucket_sort_kernel(const uint* __restrict__ ebuf, const int* __restrict__ bcur,
                        int* __restrict__ ssrc, int* __restrict__ rs, int* __restrict__ cnt,
                        float* __restrict__ dinv, int n) {
    __shared__ uint eL[BCAP];          // 24 KB
    __shared__ int hist[BNODES], ps[BNODES];
    int b = blockIdx.x, t = threadIdx.x;
    int nb = bcur[b];
    if (nb > BCAP) nb = BCAP;
    for (int i = t; i < nb; i += 256) eL[i] = ebuf[(size_t)b * BCAP + i];
    hist[t] = 0;
    __syncthreads();
    for (int i = t; i < nb; i += 256) atomicAdd(&hist[eL[i] >> 17], 1);
    __syncthreads();
    ps[t] = hist[t];
    __syncthreads();
#pragma unroll
    for (int off = 1; off < BNODES; off <<= 1) {
        int v = (t >= off) ? ps[t - off] : 0;
        __syncthreads();
        ps[t] += v;
        __syncthreads();
    }
    int excl = ps[t] - hist[t];
    int node = b * BNODES + t;
    if (node < n) {
        rs[node] = b * BCAP + excl;
        cnt[node] = hist[t];
        dinv[node] = 1.0f / sqrtf((float)hist[t] + 1.0f);
    }
    __syncthreads();
    ps[t] = excl;                      // reuse as running cursor
    __syncthreads();
    for (int i = t; i < nb; i += 256) {
        uint e = eL[i];
        int d = e >> 17;
        int p = atomicAdd(&ps[d], 1);
        ssrc[(size_t)b * BCAP + p] = (int)(e & 0x1FFFF);
    }
}

// ---------------- weight prep: fragment-ordered bf16 ----------------
// mfma_f32_16x16x32_bf16 B-frag: lane holds B[k=(lane>>4)*8+j][n=lane&15].
__global__ __launch_bounds__(256)
void wprep_kernel(const float* __restrict__ W1, const float* __restrict__ W2,
                  short8* __restrict__ W1f, short8* __restrict__ W2f) {
    int b = blockIdx.x;
    if (b < 16) {
        int f = b * 256 + threadIdx.x;
        int k0 = f >> 9, nt = (f >> 6) & 7, ln = f & 63;
        int kbase = k0 * 32 + (ln >> 4) * 8;
        int n = nt * 16 + (ln & 15);
        short8 fr;
#pragma unroll
        for (int j = 0; j < 8; ++j) fr[j] = (short)bf16_rne(W1[(kbase + j) * F_MID + n]);
        W1f[f] = fr;
    } else {
        int f = (b - 16) * 256 + threadIdx.x;
        int k0 = f >> 8, nt = (f >> 6) & 3, ln = f & 63;
        int kbase = k0 * 32 + (ln >> 4) * 8;
        int n = nt * 16 + (ln & 15);
        short8 fr;
#pragma unroll
        for (int j = 0; j < 8; ++j) fr[j] = (short)bf16_rne(W2[(kbase + j) * F_OUT + n]);
        W2f[f] = fr;
    }
}

// ---------------- MFMA GEMMs ----------------
// A: lane holds A[m=lane&15][k=(lane>>4)*8+j]; C/D: col=lane&15, row=(lane>>4)*4+reg.

// h1s[M,128](bf16) = dinv[m] * (x[M,256](fp32) @ W1bf16)
// 2-deep register prefetch of A across unrolled k0.
__global__ __launch_bounds__(256)
void gemm1_kernel(const float* __restrict__ A, const short8* __restrict__ Wf,
                  const float* __restrict__ dinv, ushort* __restrict__ C,
                  int M, int nTiles) {
    __shared__ short8 BsF[4096];   // 64 KB
    int tid = threadIdx.x;
    int lane = tid & 63, w = tid >> 6;
    for (int f = tid; f < 4096; f += 256) BsF[f] = Wf[f];
    __syncthreads();

    const float4 z4 = make_float4(0.f, 0.f, 0.f, 0.f);

    for (int t = blockIdx.x; t < nTiles; t += gridDim.x) {
        int m0 = t * 128 + w * 32;
        f32x4 acc[2][8];
#pragma unroll
        for (int mt = 0; mt < 2; ++mt)
#pragma unroll
            for (int nt = 0; nt < 8; ++nt) acc[mt][nt] = (f32x4){0.f, 0.f, 0.f, 0.f};

        // per-mt row pointers (float4 units); k0 step = 8 float4
        const float4* aptr[2];
        bool mOk[2];
#pragma unroll
        for (int mt = 0; mt < 2; ++mt) {
            int m = m0 + mt * 16 + (lane & 15);
            mOk[mt] = (m < M);
            aptr[mt] = (const float4*)&A[(size_t)(mOk[mt] ? m : 0) * F_IN + (lane >> 4) * 8];
        }

        float4 buf[2][4];   // [stage][mt*2+half]
#pragma unroll
        for (int st = 0; st < 2; ++st)
#pragma unroll
            for (int mt = 0; mt < 2; ++mt) {
                buf[st][mt * 2 + 0] = mOk[mt] ? aptr[mt][st * 8 + 0] : z4;
                buf[st][mt * 2 + 1] = mOk[mt] ? aptr[mt][st * 8 + 1] : z4;
            }

#pragma unroll
        for (int k0 = 0; k0 < 8; ++k0) {
            short8 afr[2];
#pragma unroll
            for (int mt = 0; mt < 2; ++mt) {
                float4 v0 = buf[k0 & 1][mt * 2 + 0];
                float4 v1 = buf[k0 & 1][mt * 2 + 1];
                short8 af;
                af[0] = (short)bf16_rne(v0.x); af[1] = (short)bf16_rne(v0.y);
                af[2] = (short)bf16_rne(v0.z); af[3] = (short)bf16_rne(v0.w);
                af[4] = (short)bf16_rne(v1.x); af[5] = (short)bf16_rne(v1.y);
                af[6] = (short)bf16_rne(v1.z); af[7] = (short)bf16_rne(v1.w);
                afr[mt] = af;
            }
            if (k0 < 6) {   // prefetch k0+2 into the stage just consumed
#pragma unroll
                for (int mt = 0; mt < 2; ++mt) {
                    buf[k0 & 1][mt * 2 + 0] = mOk[mt] ? aptr[mt][(k0 + 2) * 8 + 0] : z4;
                    buf[k0 & 1][mt * 2 + 1] = mOk[mt] ? aptr[mt][(k0 + 2) * 8 + 1] : z4;
                }
            }
#pragma unroll
            for (int nt = 0; nt < 8; ++nt) {
                short8 bfr = BsF[(k0 * 8 + nt) * 64 + lane];
                acc[0][nt] = __builtin_amdgcn_mfma_f32_16x16x32_bf16(afr[0], bfr, acc[0][nt], 0, 0, 0);
                acc[1][nt] = __builtin_amdgcn_mfma_f32_16x16x32_bf16(afr[1], bfr, acc[1][nt], 0, 0, 0);
            }
        }
#pragma unroll
        for (int mt = 0; mt < 2; ++mt)
#pragma unroll
            for (int i = 0; i < 4; ++i) {
                int r = m0 + mt * 16 + (lane >> 4) * 4 + i;
                if (r < M) {
                    float dv = dinv[r];
#pragma unroll
                    for (int nt = 0; nt < 8; ++nt)
                        C[(size_t)r * F_MID + nt * 16 + (lane & 15)] = bf16_rne(dv * acc[mt][nt][i]);
                }
            }
    }
}

// h2s[M,64](bf16) = dinv[m] * (h1a[M,128](bf16) @ W2bf16)
// fully unrolled; all 8 A-loads hoisted ahead of the MFMA chain.
__global__ __launch_bounds__(256)
void gemm2_kernel(const ushort* __restrict__ A, const short8* __restrict__ Wf,
                  const float* __restrict__ dinv, ushort* __restrict__ C,
                  int M, int nTiles) {
    __shared__ short8 BsF[1024];   // 16 KB
    int tid = threadIdx.x;
    int lane = tid & 63, w = tid >> 6;
    for (int f = tid; f < 1024; f += 256) BsF[f] = Wf[f];
    __syncthreads();

    for (int t = blockIdx.x; t < nTiles; t += gridDim.x) {
        int m0 = t * 128 + w * 32;
        f32x4 acc[2][4];
#pragma unroll
        for (int mt = 0; mt < 2; ++mt)
#pragma unroll
            for (int nt = 0; nt < 4; ++nt) acc[mt][nt] = (f32x4){0.f, 0.f, 0.f, 0.f};

        short8 afr[4][2];
#pragma unroll
        for (int k0 = 0; k0 < 4; ++k0)
#pragma unroll
            for (int mt = 0; mt < 2; ++mt) {
                int m = m0 + mt * 16 + (lane & 15);
                short8 af = (short8){0, 0, 0, 0, 0, 0, 0, 0};
                if (m < M) af = *(const short8*)&A[(size_t)m * F_MID + k0 * 32 + (lane >> 4) * 8];
                afr[k0][mt] = af;
            }

#pragma unroll
        for (int k0 = 0; k0 < 4; ++k0)
#pragma unroll
            for (int nt = 0; nt < 4; ++nt) {
                short8 bfr = BsF[(k0 * 4 + nt) * 64 + lane];
                acc[0][nt] = __builtin_amdgcn_mfma_f32_16x16x32_bf16(afr[k0][0], bfr, acc[0][nt], 0, 0, 0);
                acc[1][nt] = __builtin_amdgcn_mfma_f32_16x16x32_bf16(afr[k0][1], bfr, acc[1][nt], 0, 0, 0);
            }

#pragma unroll
        for (int mt = 0; mt < 2; ++mt)
#pragma unroll
            for (int i = 0; i < 4; ++i) {
                int r = m0 + mt * 16 + (lane >> 4) * 4 + i;
                if (r < M) {
                    float dv = dinv[r];
#pragma unroll
                    for (int nt = 0; nt < 4; ++nt)
                        C[(size_t)r * F_OUT + nt * 16 + (lane & 15)] = bf16_rne(dv * acc[mt][nt][i]);
                }
            }
    }
}

// ---------------- aggregation ----------------
// agg1: rows pre-scaled by dinv[src]. One wave/node; quarter q handles edge
// base+q; 16 lanes x uint4 (16B) cover the 256-B row; butterfly fold at end.
__global__ __launch_bounds__(256)
void agg1_kernel(const uint4* __restrict__ h, const int* __restrict__ rs,
                 const int* __restrict__ cnt, const int* __restrict__ ssrc,
                 const float* __restrict__ dinv, const float* __restrict__ bias,
                 uint4* __restrict__ outp, int n) {
    int w = threadIdx.x >> 6, lane = threadIdx.x & 63;
    int node = blockIdx.x * 4 + w;
    if (node >= n) return;
    int q = lane >> 4, c16 = lane & 15;
    int start = rs[node], c = cnt[node];
    float dn = dinv[node];
    float a[8];
#pragma unroll
    for (int i = 0; i < 8; ++i) a[i] = 0.f;

    for (int base = 0; base < c; base += 4) {
        int eidx = base + q;
        if (eidx < c) {
            int s = ssrc[start + eidx];
            uint4 r = h[(size_t)s * 16 + c16];
            a[0] += lo16(r.x); a[1] += hi16(r.x);
            a[2] += lo16(r.y); a[3] += hi16(r.y);
            a[4] += lo16(r.z); a[5] += hi16(r.z);
            a[6] += lo16(r.w); a[7] += hi16(r.w);
        }
    }
#pragma unroll
    for (int i = 0; i < 8; ++i) {
        a[i] += __shfl_xor(a[i], 16);
        a[i] += __shfl_xor(a[i], 32);
    }
    uint4 sr = h[(size_t)node * 16 + c16];
    const float4* b4 = (const float4*)bias;
    float4 b0 = b4[c16 * 2], b1 = b4[c16 * 2 + 1];
    float o0 = fmaxf(fmaf(dn, a[0] + lo16(sr.x), b0.x), 0.f);
    float o1 = fmaxf(fmaf(dn, a[1] + hi16(sr.x), b0.y), 0.f);
    float o2 = fmaxf(fmaf(dn, a[2] + lo16(sr.y), b0.z), 0.f);
    float o3 = fmaxf(fmaf(dn, a[3] + hi16(sr.y), b0.w), 0.f);
    float o4 = fmaxf(fmaf(dn, a[4] + lo16(sr.z), b1.x), 0.f);
    float o5 = fmaxf(fmaf(dn, a[5] + hi16(sr.z), b1.y), 0.f);
    float o6 = fmaxf(fmaf(dn, a[6] + lo16(sr.w), b1.z), 0.f);
    float o7 = fmaxf(fmaf(dn, a[7] + hi16(sr.w), b1.w), 0.f);
    if (q == 0) {
        uint4 ov;
        ov.x = pack_bf2(o0, o1);
        ov.y = pack_bf2(o2, o3);
        ov.z = pack_bf2(o4, o5);
        ov.w = pack_bf2(o6, o7);
        outp[(size_t)node * 16 + c16] = ov;
    }
}

// agg2: 64-col bf16 rows (128 B), 16 lanes x uint2; fused bias + log_softmax.
__global__ __launch_bounds__(256)
void agg2_kernel(const uint2* __restrict__ h, const int* __restrict__ rs,
                 const int* __restrict__ cnt, const int* __restrict__ ssrc,
                 const float* __restrict__ dinv, const float* __restrict__ bias,
                 float4* __restrict__ out4, int n) {
    int w = threadIdx.x >> 6, lane = threadIdx.x & 63;
    int node = blockIdx.x * 4 + w;
    if (node >= n) return;
    int q = lane >> 4, c16 = lane & 15;
    int start = rs[node], c = cnt[node];
    float dn = dinv[node];
    float a[4];
#pragma unroll
    for (int i = 0; i < 4; ++i) a[i] = 0.f;

    for (int base = 0; base < c; base += 4) {
        int eidx = base + q;
        if (eidx < c) {
            int s = ssrc[start + eidx];
            uint2 r = h[(size_t)s * 16 + c16];
            a[0] += lo16(r.x); a[1] += hi16(r.x);
            a[2] += lo16(r.y); a[3] += hi16(r.y);
        }
    }
#pragma unroll
    for (int i = 0; i < 4; ++i) {
        a[i] += __shfl_xor(a[i], 16);
        a[i] += __shfl_xor(a[i], 32);
    }
    uint2 sr = h[(size_t)node * 16 + c16];
    float4 bv = ((const float4*)bias)[c16];
    float v0 = fmaf(dn, a[0] + lo16(sr.x), bv.x);
    float v1 = fmaf(dn, a[1] + hi16(sr.x), bv.y);
    float v2 = fmaf(dn, a[2] + lo16(sr.y), bv.z);
    float v3 = fmaf(dn, a[3] + hi16(sr.y), bv.w);
    float m = fmaxf(fmaxf(v0, v1), fmaxf(v2, v3));
#pragma unroll
    for (int off = 1; off < 16; off <<= 1) m = fmaxf(m, __shfl_xor(m, off));
    float ssum = expf(v0 - m) + expf(v1 - m) + expf(v2 - m) + expf(v3 - m);
#pragma unroll
    for (int off = 1; off < 16; off <<= 1) ssum += __shfl_xor(ssum, off);
    float lg = m + logf(ssum);
    if (q == 0) out4[(size_t)node * 16 + c16] = make_float4(v0 - lg, v1 - lg, v2 - lg, v3 - lg);
}

// ---------------- launch ----------------

extern "C" void kernel_launch(void* const* d_in, const int* in_sizes, int n_in,
                              void* d_out, int out_size, void* d_ws, size_t ws_size,
                              hipStream_t stream) {
    const float* x  = (const float*)d_in[0];
    const int*   ei = (const int*)d_in[1];
    const float* W1 = (const float*)d_in[2];
    const float* b1 = (const float*)d_in[3];
    const float* W2 = (const float*)d_in[4];
    const float* b2 = (const float*)d_in[5];
    float* out = (float*)d_out;

    const int N = N_NODES;
    const int E = in_sizes[1] / 2;
    const int* src = ei;
    const int* dst = ei + E;

    char* ws = (char*)d_ws;
    size_t off = 0;
    auto alloc = [&](size_t bytes) {
        char* p = ws + off;
        off = (off + bytes + 255) & ~(size_t)255;
        return p;
    };
    int*    bcur   = (int*)alloc(NBUCKETS * 4);
    int*    rs     = (int*)alloc(N * 4);
    int*    cnt    = (int*)alloc(N * 4);
    float*  dinv   = (float*)alloc(N * 4);
    short8* W1f    = (short8*)alloc(4096 * 16);
    short8* W2f    = (short8*)alloc(1024 * 16);
    uint*   ebuf   = (uint*)alloc((size_t)NBUCKETS * BCAP * 4);   // 9.6 MB
    int*    ssrc   = (int*)alloc((size_t)NBUCKETS * BCAP * 4);    // 9.6 MB
    uint*   h1     = (uint*)alloc((size_t)N * 64 * 4);            // 128 bf16/row
    uint*   h1a    = (uint*)alloc((size_t)N * 64 * 4);
    ushort* h2     = (ushort*)h1;                                 // h1 dead after agg1

    const int nScatBlocks = (E + EPB - 1) / EPB;         // 391
    const int nAggBlocks  = (N + 3) / 4;
    const int nTiles      = (N + 127) / 128;             // 782
    const int nGemmGrid   = 512;

    hipMemsetAsync(bcur, 0, NBUCKETS * 4, stream);
    wprep_kernel<<<20, 256, 0, stream>>>(W1, W2, W1f, W2f);

    bucket_scatter_kernel<<<nScatBlocks, 256, 0, stream>>>(src, dst, bcur, ebuf, E);
    bucket_sort_kernel<<<NBUCKETS, 256, 0, stream>>>(ebuf, bcur, ssrc, rs, cnt, dinv, N);

    gemm1_kernel<<<nGemmGrid, 256, 0, stream>>>(x, W1f, dinv, (ushort*)h1, N, nTiles);
    agg1_kernel<<<nAggBlocks, 256, 0, stream>>>((const uint4*)h1, rs, cnt, ssrc, dinv, b1,
                                                (uint4*)h1a, N);
    gemm2_kernel<<<nGemmGrid, 256, 0, stream>>>((const ushort*)h1a, W2f, dinv, h2, N, nTiles);
    agg2_kernel<<<nAggBlocks, 256, 0, stream>>>((const uint2*)h2, rs, cnt, ssrc, dinv, b2,
                                                (float4*)out, N);
}

// Round 7
// 412.021 us; speedup vs baseline: 1.0272x; 1.0272x over previous
//
#include <hip/hip_runtime.h>
#include <hip/hip_bf16.h>

// GCN 2-layer: out = log_softmax(GCN2(relu(GCN1(x))))
// Round 7: GEMMs restructured for occupancy -- 512-thread blocks (8 waves),
// one 16-row m-subtile per wave (acc 32/16 VGPRs instead of 64/32), grid =
// one tile per block. Latency hiding via TLP (32 waves/CU theoretical) not
// per-wave prefetch depth (R6's failed experiment).
// Sort pipeline and aggs unchanged from R5/R6.

#define N_NODES 100000
#define F_IN 256
#define F_MID 128
#define F_OUT 64

#define BSHIFT 8                      // 256 nodes per bucket
#define BNODES 256
#define NBUCKETS ((N_NODES + BNODES - 1) / BNODES)   // 391
#define BCAP 6144                     // mean 4096, sigma ~64 -> +32 sigma
#define EPB 4096                      // edges per scatter block

typedef __attribute__((ext_vector_type(8))) short short8;
typedef __attribute__((ext_vector_type(4))) float f32x4;

__device__ inline ushort bf16_rne(float f) {
    uint u = __float_as_uint(f);
    u += 0x7FFF + ((u >> 16) & 1);
    return (ushort)(u >> 16);
}
__device__ inline float lo16(uint r) { return __uint_as_float(r << 16); }
__device__ inline float hi16(uint r) { return __uint_as_float(r & 0xffff0000u); }
__device__ inline uint pack_bf2(float a, float b) {
    return (uint)bf16_rne(a) | ((uint)bf16_rne(b) << 16);
}

// ---------------- two-level bucket sort ----------------

// S1: block-binned scatter. packed = (dst&255)<<17 | src  (25 bits)
__global__ __launch_bounds__(256)
void bucket_scatter_kernel(const int* __restrict__ src, const int* __restrict__ dst,
                           int* __restrict__ bcur, uint* __restrict__ ebuf, int E) {
    __shared__ int curL[NBUCKETS];
    int t = threadIdx.x;
    int e0 = blockIdx.x * EPB;
    int e1 = e0 + EPB; if (e1 > E) e1 = E;

    for (int i = t; i < NBUCKETS; i += 256) curL[i] = 0;
    __syncthreads();
    for (int i = e0 + t; i < e1; i += 256) atomicAdd(&curL[dst[i] >> BSHIFT], 1);
    __syncthreads();
    for (int i = t; i < NBUCKETS; i += 256) {
        int h = curL[i];
        curL[i] = h ? atomicAdd(&bcur[i], h) : 0;
    }
    __syncthreads();
    for (int i = e0 + t; i < e1; i += 256) {
        int d = dst[i], s = src[i];
        int b = d >> BSHIFT;
        int pos = atomicAdd(&curL[b], 1);
        if (pos < BCAP) ebuf[(size_t)b * BCAP + pos] = ((uint)(d & (BNODES - 1)) << 17) | (uint)s;
    }
}

// S2: per-bucket counting sort; emits ssrc + rs + cnt + dinv.
__global__ __launch_bounds__(256)
void bucket_sort_kernel(const uint* __restrict__ ebuf, const int* __restrict__ bcur,
                        int* __restrict__ ssrc, int* __restrict__ rs, int* __restrict__ cnt,
                        float* __restrict__ dinv, int n) {
    __shared__ uint eL[BCAP];          // 24 KB
    __shared__ int hist[BNODES], ps[BNODES];
    int b = blockIdx.x, t = threadIdx.x;
    int nb = bcur[b];
    if (nb > BCAP) nb = BCAP;
    for (int i = t; i < nb; i += 256) eL[i] = ebuf[(size_t)b * BCAP + i];
    hist[t] = 0;
    __syncthreads();
    for (int i = t; i < nb; i += 256) atomicAdd(&hist[eL[i] >> 17], 1);
    __syncthreads();
    ps[t] = hist[t];
    __syncthreads();
#pragma unroll
    for (int off = 1; off < BNODES; off <<= 1) {
        int v = (t >= off) ? ps[t - off] : 0;
        __syncthreads();
        ps[t] += v;
        __syncthreads();
    }
    int excl = ps[t] - hist[t];
    int node = b * BNODES + t;
    if (node < n) {
        rs[node] = b * BCAP + excl;
        cnt[node] = hist[t];
        dinv[node] = 1.0f / sqrtf((float)hist[t] + 1.0f);
    }
    __syncthreads();
    ps[t] = excl;                      // reuse as running cursor
    __syncthreads();
    for (int i = t; i < nb; i += 256) {
        uint e = eL[i];
        int d = e >> 17;
        int p = atomicAdd(&ps[d], 1);
        ssrc[(size_t)b * BCAP + p] = (int)(e & 0x1FFFF);
    }
}

// ---------------- weight prep: fragment-ordered bf16 ----------------
// mfma_f32_16x16x32_bf16 B-frag: lane holds B[k=(lane>>4)*8+j][n=lane&15].
__global__ __launch_bounds__(256)
void wprep_kernel(const float* __restrict__ W1, const float* __restrict__ W2,
                  short8* __restrict__ W1f, short8* __restrict__ W2f) {
    int b = blockIdx.x;
    if (b < 16) {
        int f = b * 256 + threadIdx.x;
        int k0 = f >> 9, nt = (f >> 6) & 7, ln = f & 63;
        int kbase = k0 * 32 + (ln >> 4) * 8;
        int n = nt * 16 + (ln & 15);
        short8 fr;
#pragma unroll
        for (int j = 0; j < 8; ++j) fr[j] = (short)bf16_rne(W1[(kbase + j) * F_MID + n]);
        W1f[f] = fr;
    } else {
        int f = (b - 16) * 256 + threadIdx.x;
        int k0 = f >> 8, nt = (f >> 6) & 3, ln = f & 63;
        int kbase = k0 * 32 + (ln >> 4) * 8;
        int n = nt * 16 + (ln & 15);
        short8 fr;
#pragma unroll
        for (int j = 0; j < 8; ++j) fr[j] = (short)bf16_rne(W2[(kbase + j) * F_OUT + n]);
        W2f[f] = fr;
    }
}

// ---------------- MFMA GEMMs ----------------
// A: lane holds A[m=lane&15][k=(lane>>4)*8+j]; C/D: col=lane&15, row=(lane>>4)*4+reg.

// h1s[M,128](bf16) = dinv[m] * (x[M,256](fp32) @ W1bf16)
// 8 waves x 16 rows = 128-row tile; one tile per block.
__global__ __launch_bounds__(512, 4)
void gemm1_kernel(const float* __restrict__ A, const short8* __restrict__ Wf,
                  const float* __restrict__ dinv, ushort* __restrict__ C,
                  int M) {
    __shared__ short8 BsF[4096];   // 64 KB
    int tid = threadIdx.x;
    int lane = tid & 63, w = tid >> 6;        // w in 0..7
    for (int f = tid; f < 4096; f += 512) BsF[f] = Wf[f];
    __syncthreads();

    const float4 z4 = make_float4(0.f, 0.f, 0.f, 0.f);
    int m0 = blockIdx.x * 128 + w * 16;
    int m = m0 + (lane & 15);
    bool mOk = (m < M);
    const float4* aptr = (const float4*)&A[(size_t)(mOk ? m : 0) * F_IN + (lane >> 4) * 8];

    f32x4 acc[8];
#pragma unroll
    for (int nt = 0; nt < 8; ++nt) acc[nt] = (f32x4){0.f, 0.f, 0.f, 0.f};

    float4 v0 = mOk ? aptr[0] : z4;
    float4 v1 = mOk ? aptr[1] : z4;

#pragma unroll
    for (int k0 = 0; k0 < 8; ++k0) {
        short8 af;
        af[0] = (short)bf16_rne(v0.x); af[1] = (short)bf16_rne(v0.y);
        af[2] = (short)bf16_rne(v0.z); af[3] = (short)bf16_rne(v0.w);
        af[4] = (short)bf16_rne(v1.x); af[5] = (short)bf16_rne(v1.y);
        af[6] = (short)bf16_rne(v1.z); af[7] = (short)bf16_rne(v1.w);
        if (k0 < 7) {   // 1-deep prefetch of next K-step
            v0 = mOk ? aptr[(k0 + 1) * 8 + 0] : z4;
            v1 = mOk ? aptr[(k0 + 1) * 8 + 1] : z4;
        }
#pragma unroll
        for (int nt = 0; nt < 8; ++nt) {
            short8 bfr = BsF[(k0 * 8 + nt) * 64 + lane];
            acc[nt] = __builtin_amdgcn_mfma_f32_16x16x32_bf16(af, bfr, acc[nt], 0, 0, 0);
        }
    }
#pragma unroll
    for (int i = 0; i < 4; ++i) {
        int r = m0 + (lane >> 4) * 4 + i;
        if (r < M) {
            float dv = dinv[r];
#pragma unroll
            for (int nt = 0; nt < 8; ++nt)
                C[(size_t)r * F_MID + nt * 16 + (lane & 15)] = bf16_rne(dv * acc[nt][i]);
        }
    }
}

// h2s[M,64](bf16) = dinv[m] * (h1a[M,128](bf16) @ W2bf16)
__global__ __launch_bounds__(512, 4)
void gemm2_kernel(const ushort* __restrict__ A, const short8* __restrict__ Wf,
                  const float* __restrict__ dinv, ushort* __restrict__ C,
                  int M) {
    __shared__ short8 BsF[1024];   // 16 KB
    int tid = threadIdx.x;
    int lane = tid & 63, w = tid >> 6;
    for (int f = tid; f < 1024; f += 512) BsF[f] = Wf[f];
    __syncthreads();

    int m0 = blockIdx.x * 128 + w * 16;
    int m = m0 + (lane & 15);
    bool mOk = (m < M);

    f32x4 acc[4];
#pragma unroll
    for (int nt = 0; nt < 4; ++nt) acc[nt] = (f32x4){0.f, 0.f, 0.f, 0.f};

    short8 afr[4];
#pragma unroll
    for (int k0 = 0; k0 < 4; ++k0) {
        short8 af = (short8){0, 0, 0, 0, 0, 0, 0, 0};
        if (mOk) af = *(const short8*)&A[(size_t)m * F_MID + k0 * 32 + (lane >> 4) * 8];
        afr[k0] = af;
    }
#pragma unroll
    for (int k0 = 0; k0 < 4; ++k0)
#pragma unroll
        for (int nt = 0; nt < 4; ++nt) {
            short8 bfr = BsF[(k0 * 4 + nt) * 64 + lane];
            acc[nt] = __builtin_amdgcn_mfma_f32_16x16x32_bf16(afr[k0], bfr, acc[nt], 0, 0, 0);
        }
#pragma unroll
    for (int i = 0; i < 4; ++i) {
        int r = m0 + (lane >> 4) * 4 + i;
        if (r < M) {
            float dv = dinv[r];
#pragma unroll
            for (int nt = 0; nt < 4; ++nt)
                C[(size_t)r * F_OUT + nt * 16 + (lane & 15)] = bf16_rne(dv * acc[nt][i]);
        }
    }
}

// ---------------- aggregation ----------------
// agg1: rows pre-scaled by dinv[src]. One wave/node; quarter q handles edge
// base+q; 16 lanes x uint4 (16B) cover the 256-B row; butterfly fold at end.
__global__ __launch_bounds__(256)
void agg1_kernel(const uint4* __restrict__ h, const int* __restrict__ rs,
                 const int* __restrict__ cnt, const int* __restrict__ ssrc,
                 const float* __restrict__ dinv, const float* __restrict__ bias,
                 uint4* __restrict__ outp, int n) {
    int w = threadIdx.x >> 6, lane = threadIdx.x & 63;
    int node = blockIdx.x * 4 + w;
    if (node >= n) return;
    int q = lane >> 4, c16 = lane & 15;
    int start = rs[node], c = cnt[node];
    float dn = dinv[node];
    float a[8];
#pragma unroll
    for (int i = 0; i < 8; ++i) a[i] = 0.f;

    for (int base = 0; base < c; base += 4) {
        int eidx = base + q;
        if (eidx < c) {
            int s = ssrc[start + eidx];
            uint4 r = h[(size_t)s * 16 + c16];
            a[0] += lo16(r.x); a[1] += hi16(r.x);
            a[2] += lo16(r.y); a[3] += hi16(r.y);
            a[4] += lo16(r.z); a[5] += hi16(r.z);
            a[6] += lo16(r.w); a[7] += hi16(r.w);
        }
    }
#pragma unroll
    for (int i = 0; i < 8; ++i) {
        a[i] += __shfl_xor(a[i], 16);
        a[i] += __shfl_xor(a[i], 32);
    }
    uint4 sr = h[(size_t)node * 16 + c16];
    const float4* b4 = (const float4*)bias;
    float4 b0 = b4[c16 * 2], b1 = b4[c16 * 2 + 1];
    float o0 = fmaxf(fmaf(dn, a[0] + lo16(sr.x), b0.x), 0.f);
    float o1 = fmaxf(fmaf(dn, a[1] + hi16(sr.x), b0.y), 0.f);
    float o2 = fmaxf(fmaf(dn, a[2] + lo16(sr.y), b0.z), 0.f);
    float o3 = fmaxf(fmaf(dn, a[3] + hi16(sr.y), b0.w), 0.f);
    float o4 = fmaxf(fmaf(dn, a[4] + lo16(sr.z), b1.x), 0.f);
    float o5 = fmaxf(fmaf(dn, a[5] + hi16(sr.z), b1.y), 0.f);
    float o6 = fmaxf(fmaf(dn, a[6] + lo16(sr.w), b1.z), 0.f);
    float o7 = fmaxf(fmaf(dn, a[7] + hi16(sr.w), b1.w), 0.f);
    if (q == 0) {
        uint4 ov;
        ov.x = pack_bf2(o0, o1);
        ov.y = pack_bf2(o2, o3);
        ov.z = pack_bf2(o4, o5);
        ov.w = pack_bf2(o6, o7);
        outp[(size_t)node * 16 + c16] = ov;
    }
}

// agg2: 64-col bf16 rows (128 B), 16 lanes x uint2; fused bias + log_softmax.
__global__ __launch_bounds__(256)
void agg2_kernel(const uint2* __restrict__ h, const int* __restrict__ rs,
                 const int* __restrict__ cnt, const int* __restrict__ ssrc,
                 const float* __restrict__ dinv, const float* __restrict__ bias,
                 float4* __restrict__ out4, int n) {
    int w = threadIdx.x >> 6, lane = threadIdx.x & 63;
    int node = blockIdx.x * 4 + w;
    if (node >= n) return;
    int q = lane >> 4, c16 = lane & 15;
    int start = rs[node], c = cnt[node];
    float dn = dinv[node];
    float a[4];
#pragma unroll
    for (int i = 0; i < 4; ++i) a[i] = 0.f;

    for (int base = 0; base < c; base += 4) {
        int eidx = base + q;
        if (eidx < c) {
            int s = ssrc[start + eidx];
            uint2 r = h[(size_t)s * 16 + c16];
            a[0] += lo16(r.x); a[1] += hi16(r.x);
            a[2] += lo16(r.y); a[3] += hi16(r.y);
        }
    }
#pragma unroll
    for (int i = 0; i < 4; ++i) {
        a[i] += __shfl_xor(a[i], 16);
        a[i] += __shfl_xor(a[i], 32);
    }
    uint2 sr = h[(size_t)node * 16 + c16];
    float4 bv = ((const float4*)bias)[c16];
    float v0 = fmaf(dn, a[0] + lo16(sr.x), bv.x);
    float v1 = fmaf(dn, a[1] + hi16(sr.x), bv.y);
    float v2 = fmaf(dn, a[2] + lo16(sr.y), bv.z);
    float v3 = fmaf(dn, a[3] + hi16(sr.y), bv.w);
    float m = fmaxf(fmaxf(v0, v1), fmaxf(v2, v3));
#pragma unroll
    for (int off = 1; off < 16; off <<= 1) m = fmaxf(m, __shfl_xor(m, off));
    float ssum = expf(v0 - m) + expf(v1 - m) + expf(v2 - m) + expf(v3 - m);
#pragma unroll
    for (int off = 1; off < 16; off <<= 1) ssum += __shfl_xor(ssum, off);
    float lg = m + logf(ssum);
    if (q == 0) out4[(size_t)node * 16 + c16] = make_float4(v0 - lg, v1 - lg, v2 - lg, v3 - lg);
}

// ---------------- launch ----------------

extern "C" void kernel_launch(void* const* d_in, const int* in_sizes, int n_in,
                              void* d_out, int out_size, void* d_ws, size_t ws_size,
                              hipStream_t stream) {
    const float* x  = (const float*)d_in[0];
    const int*   ei = (const int*)d_in[1];
    const float* W1 = (const float*)d_in[2];
    const float* b1 = (const float*)d_in[3];
    const float* W2 = (const float*)d_in[4];
    const float* b2 = (const float*)d_in[5];
    float* out = (float*)d_out;

    const int N = N_NODES;
    const int E = in_sizes[1] / 2;
    const int* src = ei;
    const int* dst = ei + E;

    char* ws = (char*)d_ws;
    size_t off = 0;
    auto alloc = [&](size_t bytes) {
        char* p = ws + off;
        off = (off + bytes + 255) & ~(size_t)255;
        return p;
    };
    int*    bcur   = (int*)alloc(NBUCKETS * 4);
    int*    rs     = (int*)alloc(N * 4);
    int*    cnt    = (int*)alloc(N * 4);
    float*  dinv   = (float*)alloc(N * 4);
    short8* W1f    = (short8*)alloc(4096 * 16);
    short8* W2f    = (short8*)alloc(1024 * 16);
    uint*   ebuf   = (uint*)alloc((size_t)NBUCKETS * BCAP * 4);   // 9.6 MB
    int*    ssrc   = (int*)alloc((size_t)NBUCKETS * BCAP * 4);    // 9.6 MB
    uint*   h1     = (uint*)alloc((size_t)N * 64 * 4);            // 128 bf16/row
    uint*   h1a    = (uint*)alloc((size_t)N * 64 * 4);
    ushort* h2     = (ushort*)h1;                                 // h1 dead after agg1

    const int nScatBlocks = (E + EPB - 1) / EPB;         // 391
    const int nAggBlocks  = (N + 3) / 4;
    const int nTiles      = (N + 127) / 128;             // 782

    hipMemsetAsync(bcur, 0, NBUCKETS * 4, stream);
    wprep_kernel<<<20, 256, 0, stream>>>(W1, W2, W1f, W2f);

    bucket_scatter_kernel<<<nScatBlocks, 256, 0, stream>>>(src, dst, bcur, ebuf, E);
    bucket_sort_kernel<<<NBUCKETS, 256, 0, stream>>>(ebuf, bcur, ssrc, rs, cnt, dinv, N);

    gemm1_kernel<<<nTiles, 512, 0, stream>>>(x, W1f, dinv, (ushort*)h1, N);
    agg1_kernel<<<nAggBlocks, 256, 0, stream>>>((const uint4*)h1, rs, cnt, ssrc, dinv, b1,
                                                (uint4*)h1a, N);
    gemm2_kernel<<<nTiles, 512, 0, stream>>>((const ushort*)h1a, W2f, dinv, h2, N);
    agg2_kernel<<<nAggBlocks, 256, 0, stream>>>((const uint2*)h2, rs, cnt, ssrc, dinv, b2,
                                                (float4*)out, N);
}